// Round 1
// baseline (1886.541 us; speedup 1.0000x reference)
//
#include <hip/hip_runtime.h>

#define C    128
#define C3   384
#define ROWS 64   // rows per block

// ---------------------------------------------------------------------------
// K0: transpose w_ih/w_hh [3C][C] -> k-major wT [C][3C] so GEMM reads coalesce
// ---------------------------------------------------------------------------
__global__ __launch_bounds__(256) void build_wT(const float* __restrict__ w_ih,
                                                const float* __restrict__ w_hh,
                                                float* __restrict__ wT_ih,
                                                float* __restrict__ wT_hh) {
    int i = blockIdx.x * 256 + threadIdx.x;
    if (i < C3 * C) {
        int r = i / C, c = i % C;           // w[r][c], r in [0,384)
        wT_ih[c * C3 + r] = w_ih[i];
        wT_hh[c * C3 + r] = w_hh[i];
    }
}

// ---------------------------------------------------------------------------
// K1: m = x @ W   (x [N,128] row-major, W [128,128] row-major)
// 64 rows/block, 256 threads; thread = (r0 group of 8 rows) x (4 cols)
// ---------------------------------------------------------------------------
__global__ __launch_bounds__(256) void gemm_m(const float* __restrict__ x,
                                              const float* __restrict__ W,
                                              float* __restrict__ m, int N) {
    __shared__ float xs[ROWS][C + 4];
    const int block_row = blockIdx.x * ROWS;
    const int tid = threadIdx.x;

    // stage x tile (float4, coalesced)
    for (int t = tid; t < ROWS * 32; t += 256) {
        int r = t >> 5, c4 = (t & 31) << 2;
        int gr = block_row + r;
        float4 v = make_float4(0.f, 0.f, 0.f, 0.f);
        if (gr < N) v = *(const float4*)&x[(size_t)gr * C + c4];
        *(float4*)&xs[r][c4] = v;
    }
    __syncthreads();

    const int cb = tid & 31;          // col base 0..31
    const int r0 = (tid >> 5) * 8;    // row base

    float acc[8][4] = {};
    #pragma unroll 2
    for (int k = 0; k < C; ++k) {
        float w0 = W[k * C + cb];
        float w1 = W[k * C + cb + 32];
        float w2 = W[k * C + cb + 64];
        float w3 = W[k * C + cb + 96];
        #pragma unroll
        for (int r = 0; r < 8; ++r) {
            float a = xs[r0 + r][k];
            acc[r][0] = fmaf(a, w0, acc[r][0]);
            acc[r][1] = fmaf(a, w1, acc[r][1]);
            acc[r][2] = fmaf(a, w2, acc[r][2]);
            acc[r][3] = fmaf(a, w3, acc[r][3]);
        }
    }
    #pragma unroll
    for (int r = 0; r < 8; ++r) {
        int gr = block_row + r0 + r;
        if (gr < N) {
            size_t base = (size_t)gr * C;
            m[base + cb]      = acc[r][0];
            m[base + cb + 32] = acc[r][1];
            m[base + cb + 64] = acc[r][2];
            m[base + cb + 96] = acc[r][3];
        }
    }
}

// ---------------------------------------------------------------------------
// K2: fused gather-sum + GRU cell.
//   agg[n] = sum_k m[e[n,k]]  (e==N -> zero row)
//   gi = agg @ w_ih^T + b_ih ; gh = h @ w_hh^T + b_hh ; GRU elementwise
// 64 rows/block, 256 threads. In-place safe: block only touches its own rows
// of h_in/h_out (gather source is m, not h).
// ---------------------------------------------------------------------------
__global__ __launch_bounds__(256) void gather_gru(
        const float* __restrict__ m, const int* __restrict__ eidx,
        const float* __restrict__ h_in, float* __restrict__ h_out,
        const float* __restrict__ wT_ih, const float* __restrict__ wT_hh,
        const float* __restrict__ b_ih, const float* __restrict__ b_hh,
        int N, int K) {
    __shared__ float ags[ROWS][C + 4];
    __shared__ float hs[ROWS][C + 4];
    const int block_row = blockIdx.x * ROWS;
    const int tid = threadIdx.x;

    // gather phase + h staging: task = (row, float4 chunk)
    for (int t = tid; t < ROWS * 32; t += 256) {
        int r = t >> 5, c4 = (t & 31) << 2;
        int gr = block_row + r;
        float4 acc = make_float4(0.f, 0.f, 0.f, 0.f);
        float4 hv  = make_float4(0.f, 0.f, 0.f, 0.f);
        if (gr < N) {
            const int* e = &eidx[(size_t)gr * K];
            for (int k = 0; k < K; ++k) {
                int ei = e[k];
                if (ei < N) {
                    float4 v = *(const float4*)&m[(size_t)ei * C + c4];
                    acc.x += v.x; acc.y += v.y; acc.z += v.z; acc.w += v.w;
                }
            }
            hv = *(const float4*)&h_in[(size_t)gr * C + c4];
        }
        *(float4*)&ags[r][c4] = acc;
        *(float4*)&hs[r][c4]  = hv;
    }
    __syncthreads();

    const int c_idx = tid & 31;
    const int r0 = (tid >> 5) * 8;

    // two column groups of 64 (each thread: 2 cols x 8 rows x 6 gate blocks)
    #pragma unroll 1
    for (int cg = 0; cg < 2; ++cg) {
        const int c0 = cg * 64 + c_idx;
        const int c1 = c0 + 32;

        float a_ir[8][2] = {}, a_iz[8][2] = {}, a_in[8][2] = {};
        float a_hr[8][2] = {}, a_hz[8][2] = {}, a_hn[8][2] = {};

        #pragma unroll 2
        for (int k = 0; k < C; ++k) {
            const float* wi = &wT_ih[(size_t)k * C3];
            const float* wh = &wT_hh[(size_t)k * C3];
            float wir0 = wi[c0],        wir1 = wi[c1];
            float wiz0 = wi[128 + c0],  wiz1 = wi[128 + c1];
            float win0 = wi[256 + c0],  win1 = wi[256 + c1];
            float whr0 = wh[c0],        whr1 = wh[c1];
            float whz0 = wh[128 + c0],  whz1 = wh[128 + c1];
            float whn0 = wh[256 + c0],  whn1 = wh[256 + c1];
            #pragma unroll
            for (int r = 0; r < 8; ++r) {
                float a = ags[r0 + r][k];
                float h = hs[r0 + r][k];
                a_ir[r][0] = fmaf(a, wir0, a_ir[r][0]);
                a_ir[r][1] = fmaf(a, wir1, a_ir[r][1]);
                a_iz[r][0] = fmaf(a, wiz0, a_iz[r][0]);
                a_iz[r][1] = fmaf(a, wiz1, a_iz[r][1]);
                a_in[r][0] = fmaf(a, win0, a_in[r][0]);
                a_in[r][1] = fmaf(a, win1, a_in[r][1]);
                a_hr[r][0] = fmaf(h, whr0, a_hr[r][0]);
                a_hr[r][1] = fmaf(h, whr1, a_hr[r][1]);
                a_hz[r][0] = fmaf(h, whz0, a_hz[r][0]);
                a_hz[r][1] = fmaf(h, whz1, a_hz[r][1]);
                a_hn[r][0] = fmaf(h, whn0, a_hn[r][0]);
                a_hn[r][1] = fmaf(h, whn1, a_hn[r][1]);
            }
        }

        // elementwise GRU + store
        #pragma unroll
        for (int r = 0; r < 8; ++r) {
            int gr = block_row + r0 + r;
            if (gr >= N) continue;
            #pragma unroll
            for (int j = 0; j < 2; ++j) {
                int c = (j == 0) ? c0 : c1;
                float ir = a_ir[r][j] + b_ih[c];
                float iz = a_iz[r][j] + b_ih[128 + c];
                float in_ = a_in[r][j] + b_ih[256 + c];
                float hr = a_hr[r][j] + b_hh[c];
                float hz = a_hz[r][j] + b_hh[128 + c];
                float hn = a_hn[r][j] + b_hh[256 + c];
                float rg = 1.f / (1.f + __expf(-(ir + hr)));
                float zg = 1.f / (1.f + __expf(-(iz + hz)));
                float ng = tanhf(in_ + rg * hn);
                float hv = hs[r0 + r][c];
                h_out[(size_t)gr * C + c] = (1.f - zg) * ng + zg * hv;
            }
        }
    }
}

// ---------------------------------------------------------------------------
extern "C" void kernel_launch(void* const* d_in, const int* in_sizes, int n_in,
                              void* d_out, int out_size, void* d_ws, size_t ws_size,
                              hipStream_t stream) {
    const float* x      = (const float*)d_in[0];
    const int*   eidx   = (const int*)  d_in[1];
    const float* weight = (const float*)d_in[2];
    const float* w_ih   = (const float*)d_in[3];
    const float* w_hh   = (const float*)d_in[4];
    const float* b_ih   = (const float*)d_in[5];
    const float* b_hh   = (const float*)d_in[6];
    float* out = (float*)d_out;

    const int N = in_sizes[0] / C;
    const int K = in_sizes[1] / N;

    char* ws = (char*)d_ws;
    float* m     = (float*)ws;                              // N*C f32
    float* wT_ih = (float*)(ws + (size_t)N * C * 4);        // C*3C f32
    float* wT_hh = wT_ih + (size_t)C * C3;                  // C*3C f32

    build_wT<<<(C3 * C + 255) / 256, 256, 0, stream>>>(w_ih, w_hh, wT_ih, wT_hh);

    const int nblocks = (N + ROWS - 1) / ROWS;
    for (int layer = 0; layer < 3; ++layer) {
        const float* xin = (layer == 0) ? x : out;
        gemm_m<<<nblocks, 256, 0, stream>>>(xin, weight + (size_t)layer * C * C, m, N);
        gather_gru<<<nblocks, 256, 0, stream>>>(m, eidx, xin, out,
                                                wT_ih, wT_hh, b_ih, b_hh, N, K);
    }
}

// Round 2
// 1153.937 us; speedup vs baseline: 1.6349x; 1.6349x over previous
//
#include <hip/hip_runtime.h>

#define CDIM 128
#define C3   384
#define NLAYER 3

typedef __attribute__((ext_vector_type(8))) __bf16 bf16x8;
typedef __attribute__((ext_vector_type(4))) __bf16 bf16x4;
typedef __attribute__((ext_vector_type(4))) float  f32x4;

static __device__ inline f32x4 mfma16(bf16x8 a, bf16x8 b, f32x4 c) {
    return __builtin_amdgcn_mfma_f32_16x16x32_bf16(a, b, c, 0, 0, 0);
}

// ---------------------------------------------------------------------------
// prep 1: wT[j][c] = w_ih[c][j]   (k-major for the Wc GEMM)
// ---------------------------------------------------------------------------
__global__ __launch_bounds__(256) void prep_transpose(const float* __restrict__ w_ih,
                                                      float* __restrict__ wT) {
    int idx = blockIdx.x * 256 + threadIdx.x;       // 128*384
    int j = idx / C3, c = idx % C3;
    wT[idx] = w_ih[c * CDIM + j];
}

// ---------------------------------------------------------------------------
// prep 2: Wc[l][p][c] = sum_j W[l][p][j] * w_ih[c][j]   (block = l*128+p)
// ---------------------------------------------------------------------------
__global__ __launch_bounds__(256) void prep_wc(const float* __restrict__ weight,
                                               const float* __restrict__ wT,
                                               float* __restrict__ Wc) {
    __shared__ float wrow[CDIM];
    const int b = blockIdx.x;                        // l*128 + p
    if (threadIdx.x < CDIM) wrow[threadIdx.x] = weight[(size_t)b * CDIM + threadIdx.x];
    __syncthreads();
    for (int c = threadIdx.x; c < C3; c += 256) {
        float acc = 0.f;
        #pragma unroll 8
        for (int j = 0; j < CDIM; ++j) acc = fmaf(wrow[j], wT[j * C3 + c], acc);
        Wc[(size_t)b * C3 + c] = acc;
    }
}

// ---------------------------------------------------------------------------
// prep 3: pack V[256][512] (= [s_r | s_z | i_n | h_n] blocks) into MFMA
// fragment order, split bf16 hi/lo.  frag(kt,ct): lane l, j ->
//   V[k = kt*32 + (l>>4)*8 + j][c = ct*16 + (l&15)]
// ---------------------------------------------------------------------------
__global__ __launch_bounds__(256) void prep_pack(const float* __restrict__ Wc,
                                                 const float* __restrict__ w_hh,
                                                 __bf16* __restrict__ vfh,
                                                 __bf16* __restrict__ vfl) {
    const int fid  = blockIdx.x * 4 + (threadIdx.x >> 6);   // 0..767 = l*256 + kt*32 + ct
    const int lane = threadIdx.x & 63;
    const int l    = fid >> 8;
    const int rem  = fid & 255;
    const int kt   = rem >> 5, ct = rem & 31;
    const int kbase = kt * 32 + (lane >> 4) * 8;
    const int c     = ct * 16 + (lane & 15);

    bf16x8 H, L;
    #pragma unroll
    for (int j = 0; j < 8; ++j) {
        int k = kbase + j;
        float v;
        if (k < CDIM) {
            v = (c < C3) ? Wc[((size_t)l * CDIM + k) * C3 + c] : 0.f;
        } else {
            int q = k - CDIM;
            if (c < 256)      v = w_hh[(size_t)c * CDIM + q];          // r,z rows
            else if (c < C3)  v = 0.f;                                  // i_n has no h part
            else              v = w_hh[(size_t)(c - CDIM) * CDIM + q];  // n rows 256..383
        }
        __bf16 h = (__bf16)v;
        H[j] = h;
        L[j] = (__bf16)(v - (float)h);
    }
    size_t base = ((size_t)fid * 64 + lane) * 8;
    *(bf16x8*)&vfh[base] = H;
    *(bf16x8*)&vfl[base] = L;
}

// ---------------------------------------------------------------------------
// prep 4: bias4[c] = {b_ih[c]+b_hh[c], b_ih[128+c]+b_hh[128+c], b_ih[256+c], b_hh[256+c]}
// ---------------------------------------------------------------------------
__global__ void prep_bias(const float* __restrict__ b_ih, const float* __restrict__ b_hh,
                          float* __restrict__ bias4) {
    int c = threadIdx.x;                             // 128 threads
    float4 v = make_float4(b_ih[c] + b_hh[c],
                           b_ih[CDIM + c] + b_hh[CDIM + c],
                           b_ih[256 + c],
                           b_hh[256 + c]);
    *(float4*)&bias4[c * 4] = v;
}

// ---------------------------------------------------------------------------
// Fused layer: gather(x) -> U=[aggx|h] bf16 hi/lo in LDS -> MFMA G = U @ V
// -> LDS gate exchange -> GRU elementwise -> h_out.
// 64 rows/block, 256 threads (4 waves). Wave w owns output cols [128w,128w+128)
// == gate w (0:s_r 1:s_z 2:i_n 3:h_n). Waves 2/3 skip their zero K-half.
// ---------------------------------------------------------------------------
__global__ __launch_bounds__(256, 2) void layer_kernel(
        const float* __restrict__ xin, const int* __restrict__ eidx,
        const __bf16* __restrict__ vfh, const __bf16* __restrict__ vfl,
        const float* __restrict__ bias4, float* __restrict__ hout, int N) {
    __shared__ char smem[69632];
    float* ex  = (float*)smem;                       // [64][264] f32 (epilogue, reuses U)
    int*   eis = (int*)(smem + 65536);               // [64][16]

    const int tid  = threadIdx.x;
    const int brow = blockIdx.x * 64;

    // ---- stage edge indices (K=16): one int4 per thread ----
    {
        int r = tid >> 2, q = tid & 3;
        int gr = brow + r;
        int4 v = make_int4(N, N, N, N);
        if (gr < N) v = *(const int4*)&eidx[(size_t)gr * 16 + q * 4];
        *(int4*)&eis[tid * 4] = v;
    }
    __syncthreads();

    // ---- gather + bf16 hi/lo split into U rows (swizzled LDS) ----
    #pragma unroll 2
    for (int i = 0; i < 8; ++i) {
        int t = tid + i * 256;
        int r = t >> 5, c4 = (t & 31) << 2;
        int gr = brow + r;
        float4 acc = make_float4(0.f, 0.f, 0.f, 0.f);
        float4 hv  = make_float4(0.f, 0.f, 0.f, 0.f);
        if (gr < N) {
            const int* e = &eis[r * 16];
            #pragma unroll
            for (int k = 0; k < 16; ++k) {
                int ei = e[k];
                if (ei < N) {
                    const float4 v = *(const float4*)&xin[(size_t)ei * CDIM + c4];
                    acc.x += v.x; acc.y += v.y; acc.z += v.z; acc.w += v.w;
                }
            }
            hv = *(const float4*)&xin[(size_t)gr * CDIM + c4];
        }
        // agg part at k=c4
        {
            uint off = (uint)((r * 256 + c4) * 2) ^ (uint)((r & 7) << 4);
            __bf16 h0 = (__bf16)acc.x, h1 = (__bf16)acc.y, h2 = (__bf16)acc.z, h3 = (__bf16)acc.w;
            bf16x4 hi = {h0, h1, h2, h3};
            bf16x4 lo = {(__bf16)(acc.x - (float)h0), (__bf16)(acc.y - (float)h1),
                         (__bf16)(acc.z - (float)h2), (__bf16)(acc.w - (float)h3)};
            *(bf16x4*)(smem + off)         = hi;
            *(bf16x4*)(smem + 32768 + off) = lo;
        }
        // h part at k=128+c4
        {
            uint off = (uint)((r * 256 + 128 + c4) * 2) ^ (uint)((r & 7) << 4);
            __bf16 h0 = (__bf16)hv.x, h1 = (__bf16)hv.y, h2 = (__bf16)hv.z, h3 = (__bf16)hv.w;
            bf16x4 hi = {h0, h1, h2, h3};
            bf16x4 lo = {(__bf16)(hv.x - (float)h0), (__bf16)(hv.y - (float)h1),
                         (__bf16)(hv.z - (float)h2), (__bf16)(hv.w - (float)h3)};
            *(bf16x4*)(smem + off)         = hi;
            *(bf16x4*)(smem + 32768 + off) = lo;
        }
    }
    __syncthreads();

    // ---- MFMA phase ----
    const int wave = tid >> 6, lane = tid & 63;
    const int lrow = lane & 15, lk = (lane >> 4) * 8;
    f32x4 acc[4][8];
    #pragma unroll
    for (int a = 0; a < 4; ++a)
        #pragma unroll
        for (int b = 0; b < 8; ++b) acc[a][b] = (f32x4){0.f, 0.f, 0.f, 0.f};

    const int ktBeg = (wave == 3) ? 4 : 0;
    const int ktEnd = (wave == 2) ? 4 : 8;
    for (int kt = ktBeg; kt < ktEnd; ++kt) {
        bf16x8 ah[4], al[4];
        #pragma unroll
        for (int rt = 0; rt < 4; ++rt) {
            int row = rt * 16 + lrow;
            uint off = (uint)((row * 256 + kt * 32 + lk) * 2) ^ (uint)((row & 7) << 4);
            ah[rt] = *(const bf16x8*)(smem + off);
            al[rt] = *(const bf16x8*)(smem + 32768 + off);
        }
        const __bf16* bh_p = vfh + ((size_t)(kt * 32 + wave * 8) * 64 + lane) * 8;
        const __bf16* bl_p = vfl + ((size_t)(kt * 32 + wave * 8) * 64 + lane) * 8;
        #pragma unroll
        for (int ct = 0; ct < 8; ++ct) {
            bf16x8 bh = *(const bf16x8*)(bh_p + (size_t)ct * 512);
            bf16x8 bl = *(const bf16x8*)(bl_p + (size_t)ct * 512);
            #pragma unroll
            for (int rt = 0; rt < 4; ++rt) {
                acc[rt][ct] = mfma16(ah[rt], bh, acc[rt][ct]);
                acc[rt][ct] = mfma16(al[rt], bh, acc[rt][ct]);
                acc[rt][ct] = mfma16(ah[rt], bl, acc[rt][ct]);
            }
        }
    }
    __syncthreads();   // U dead; reuse LDS as gate-exchange buffer

    // ---- epilogue: 2 rounds of 64 cols ----
    #pragma unroll 1
    for (int rnd = 0; rnd < 2; ++rnd) {
        #pragma unroll
        for (int ct = rnd * 4; ct < rnd * 4 + 4; ++ct) {
            int cc = ct * 16 + lrow - rnd * 64;     // 0..63
            #pragma unroll
            for (int rt = 0; rt < 4; ++rt) {
                int n = rt * 16 + ((lane >> 4) << 2);
                #pragma unroll
                for (int reg = 0; reg < 4; ++reg)
                    ex[(n + reg) * 264 + cc * 4 + wave] = acc[rt][ct][reg];
            }
        }
        __syncthreads();
        {
            int c = rnd * 64 + lane;
            float4 b = *(const float4*)&bias4[c * 4];
            #pragma unroll 4
            for (int i = 0; i < 16; ++i) {
                int n = wave * 16 + i;
                int gr = brow + n;
                float4 g = *(const float4*)&ex[n * 264 + lane * 4];
                float rr = 1.f / (1.f + __expf(-(g.x + b.x)));
                float zz = 1.f / (1.f + __expf(-(g.y + b.y)));
                float nn = tanhf(g.z + b.z + rr * (g.w + b.w));
                if (gr < N) {
                    float h = xin[(size_t)gr * CDIM + c];
                    hout[(size_t)gr * CDIM + c] = (1.f - zz) * nn + zz * h;
                }
            }
        }
        __syncthreads();
    }
}

// ---------------------------------------------------------------------------
extern "C" void kernel_launch(void* const* d_in, const int* in_sizes, int n_in,
                              void* d_out, int out_size, void* d_ws, size_t ws_size,
                              hipStream_t stream) {
    const float* x      = (const float*)d_in[0];
    const int*   eidx   = (const int*)  d_in[1];
    const float* weight = (const float*)d_in[2];
    const float* w_ih   = (const float*)d_in[3];
    const float* w_hh   = (const float*)d_in[4];
    const float* b_ih   = (const float*)d_in[5];
    const float* b_hh   = (const float*)d_in[6];
    float* out = (float*)d_out;

    const int N = in_sizes[0] / CDIM;

    char* p = (char*)d_ws;
    float*  bufA  = (float*)p;  p += (size_t)N * CDIM * 4;
    float*  Wc    = (float*)p;  p += (size_t)NLAYER * CDIM * C3 * 4;
    float*  wT    = (float*)p;  p += (size_t)CDIM * C3 * 4;
    float*  bias4 = (float*)p;  p += 512 * 4;
    __bf16* vfh   = (__bf16*)p; p += (size_t)NLAYER * 131072 * 2;
    __bf16* vfl   = (__bf16*)p;

    prep_transpose<<<192, 256, 0, stream>>>(w_ih, wT);
    prep_wc<<<NLAYER * CDIM, 256, 0, stream>>>(weight, wT, Wc);
    prep_pack<<<192, 256, 0, stream>>>(Wc, w_hh, vfh, vfl);
    prep_bias<<<1, 128, 0, stream>>>(b_ih, b_hh, bias4);

    const int nb = (N + 63) / 64;
    const size_t VSZ = 131072;   // per-layer fragment elements
    layer_kernel<<<nb, 256, 0, stream>>>(x,    eidx, vfh,           vfl,           bias4, out,  N);
    layer_kernel<<<nb, 256, 0, stream>>>(out,  eidx, vfh + VSZ,     vfl + VSZ,     bias4, bufA, N);
    layer_kernel<<<nb, 256, 0, stream>>>(bufA, eidx, vfh + 2 * VSZ, vfl + 2 * VSZ, bias4, out,  N);
}

// Round 3
// 810.462 us; speedup vs baseline: 2.3277x; 1.4238x over previous
//
#include <hip/hip_runtime.h>

#define CDIM 128
#define C3   384
#define NLAYER 3
#define ROWS 32

typedef __attribute__((ext_vector_type(8))) __bf16 bf16x8;
typedef __attribute__((ext_vector_type(4))) __bf16 bf16x4;
typedef __attribute__((ext_vector_type(4))) float  f32x4;

static __device__ inline f32x4 mfma16(bf16x8 a, bf16x8 b, f32x4 c) {
    return __builtin_amdgcn_mfma_f32_16x16x32_bf16(a, b, c, 0, 0, 0);
}

// ---------------------------------------------------------------------------
// prep 1: wT[j][c] = w_ih[c][j]   (k-major for the Wc GEMM)
// ---------------------------------------------------------------------------
__global__ __launch_bounds__(256) void prep_transpose(const float* __restrict__ w_ih,
                                                      float* __restrict__ wT) {
    int idx = blockIdx.x * 256 + threadIdx.x;       // 128*384
    int j = idx / C3, c = idx % C3;
    wT[idx] = w_ih[c * CDIM + j];
}

// ---------------------------------------------------------------------------
// prep 2: Wc[l][p][c] = sum_j W[l][p][j] * w_ih[c][j]   (block = l*128+p)
// ---------------------------------------------------------------------------
__global__ __launch_bounds__(256) void prep_wc(const float* __restrict__ weight,
                                               const float* __restrict__ wT,
                                               float* __restrict__ Wc) {
    __shared__ float wrow[CDIM];
    const int b = blockIdx.x;                        // l*128 + p
    if (threadIdx.x < CDIM) wrow[threadIdx.x] = weight[(size_t)b * CDIM + threadIdx.x];
    __syncthreads();
    for (int c = threadIdx.x; c < C3; c += 256) {
        float acc = 0.f;
        #pragma unroll 8
        for (int j = 0; j < CDIM; ++j) acc = fmaf(wrow[j], wT[j * C3 + c], acc);
        Wc[(size_t)b * C3 + c] = acc;
    }
}

// ---------------------------------------------------------------------------
// prep 3: pack V[256][512] (= [s_r | s_z | i_n | h_n] blocks) into MFMA
// fragment order, split bf16 hi/lo.  frag(kt,ct): lane l, j ->
//   V[k = kt*32 + (l>>4)*8 + j][c = ct*16 + (l&15)]
// ---------------------------------------------------------------------------
__global__ __launch_bounds__(256) void prep_pack(const float* __restrict__ Wc,
                                                 const float* __restrict__ w_hh,
                                                 __bf16* __restrict__ vfh,
                                                 __bf16* __restrict__ vfl) {
    const int fid  = blockIdx.x * 4 + (threadIdx.x >> 6);   // 0..767 = l*256 + kt*32 + ct
    const int lane = threadIdx.x & 63;
    const int l    = fid >> 8;
    const int rem  = fid & 255;
    const int kt   = rem >> 5, ct = rem & 31;
    const int kbase = kt * 32 + (lane >> 4) * 8;
    const int c     = ct * 16 + (lane & 15);

    bf16x8 H, L;
    #pragma unroll
    for (int j = 0; j < 8; ++j) {
        int k = kbase + j;
        float v;
        if (k < CDIM) {
            v = (c < C3) ? Wc[((size_t)l * CDIM + k) * C3 + c] : 0.f;
        } else {
            int q = k - CDIM;
            if (c < 256)      v = w_hh[(size_t)c * CDIM + q];          // r,z rows
            else if (c < C3)  v = 0.f;                                  // i_n has no h part
            else              v = w_hh[(size_t)(c - CDIM) * CDIM + q];  // n rows 256..383
        }
        __bf16 h = (__bf16)v;
        H[j] = h;
        L[j] = (__bf16)(v - (float)h);
    }
    size_t base = ((size_t)fid * 64 + lane) * 8;
    *(bf16x8*)&vfh[base] = H;
    *(bf16x8*)&vfl[base] = L;
}

// ---------------------------------------------------------------------------
// prep 4: bias4[c] = {b_ih[c]+b_hh[c], b_ih[128+c]+b_hh[128+c], b_ih[256+c], b_hh[256+c]}
// ---------------------------------------------------------------------------
__global__ void prep_bias(const float* __restrict__ b_ih, const float* __restrict__ b_hh,
                          float* __restrict__ bias4) {
    int c = threadIdx.x;                             // 128 threads
    float4 v = make_float4(b_ih[c] + b_hh[c],
                           b_ih[CDIM + c] + b_hh[CDIM + c],
                           b_ih[256 + c],
                           b_hh[256 + c]);
    *(float4*)&bias4[c * 4] = v;
}

// ---------------------------------------------------------------------------
// Fused layer: gather(x) -> U=[aggx|h] bf16 hi/lo in LDS -> MFMA G = U @ V
// -> LDS gate exchange -> GRU elementwise -> h_out.
// 32 rows/block, 256 threads (4 waves). Wave w owns output cols [128w,128w+128)
// == gate w (0:s_r 1:s_z 2:i_n 3:h_n). Waves 2/3 skip their zero K-half.
// LDS 34.8KB -> 4 blocks/CU (16 waves/CU).
// ---------------------------------------------------------------------------
__global__ __launch_bounds__(256, 4) void layer_kernel(
        const float* __restrict__ xin, const int* __restrict__ eidx,
        const __bf16* __restrict__ vfh, const __bf16* __restrict__ vfl,
        const float* __restrict__ bias4, float* __restrict__ hout, int N) {
    __shared__ char smem[34816];
    float* ex  = (float*)smem;                       // [32][268] f32 (epilogue, reuses U)
    int*   eis = (int*)(smem + 32768);               // [32][16]

    const int tid  = threadIdx.x;
    const int brow = blockIdx.x * ROWS;

    // ---- stage edge indices (K=16): one int4 per thread (threads 0..127) ----
    if (tid < 128) {
        int r = tid >> 2, q = tid & 3;
        int gr = brow + r;
        int4 v = make_int4(N, N, N, N);
        if (gr < N) v = *(const int4*)&eidx[(size_t)gr * 16 + q * 4];
        *(int4*)&eis[tid * 4] = v;
    }
    __syncthreads();

    // ---- gather + bf16 hi/lo split into U rows (swizzled LDS) ----
    #pragma unroll 2
    for (int i = 0; i < 4; ++i) {
        int t = tid + i * 256;
        int r = t >> 5, c4 = (t & 31) << 2;
        int gr = brow + r;
        float hmsk = (gr < N) ? 1.f : 0.f;
        int   hrow = (gr < N) ? gr : 0;
        float4 acc = make_float4(0.f, 0.f, 0.f, 0.f);
        const int* e = &eis[r * 16];
        #pragma unroll
        for (int k = 0; k < 16; ++k) {
            int ei = e[k];
            float msk = (ei < N) ? 1.f : 0.f;
            int   ci  = (ei < N) ? ei : 0;
            const float4 v = *(const float4*)&xin[(size_t)ci * CDIM + c4];
            acc.x = fmaf(v.x, msk, acc.x);
            acc.y = fmaf(v.y, msk, acc.y);
            acc.z = fmaf(v.z, msk, acc.z);
            acc.w = fmaf(v.w, msk, acc.w);
        }
        float4 hv = *(const float4*)&xin[(size_t)hrow * CDIM + c4];
        hv.x *= hmsk; hv.y *= hmsk; hv.z *= hmsk; hv.w *= hmsk;

        // agg part at k=c4
        {
            uint off = (uint)((r * 256 + c4) * 2) ^ (uint)((r & 7) << 4);
            __bf16 h0 = (__bf16)acc.x, h1 = (__bf16)acc.y, h2 = (__bf16)acc.z, h3 = (__bf16)acc.w;
            bf16x4 hi = {h0, h1, h2, h3};
            bf16x4 lo = {(__bf16)(acc.x - (float)h0), (__bf16)(acc.y - (float)h1),
                         (__bf16)(acc.z - (float)h2), (__bf16)(acc.w - (float)h3)};
            *(bf16x4*)(smem + off)         = hi;
            *(bf16x4*)(smem + 16384 + off) = lo;
        }
        // h part at k=128+c4
        {
            uint off = (uint)((r * 256 + 128 + c4) * 2) ^ (uint)((r & 7) << 4);
            __bf16 h0 = (__bf16)hv.x, h1 = (__bf16)hv.y, h2 = (__bf16)hv.z, h3 = (__bf16)hv.w;
            bf16x4 hi = {h0, h1, h2, h3};
            bf16x4 lo = {(__bf16)(hv.x - (float)h0), (__bf16)(hv.y - (float)h1),
                         (__bf16)(hv.z - (float)h2), (__bf16)(hv.w - (float)h3)};
            *(bf16x4*)(smem + off)         = hi;
            *(bf16x4*)(smem + 16384 + off) = lo;
        }
    }
    __syncthreads();

    // ---- MFMA phase ----
    const int wave = tid >> 6, lane = tid & 63;
    const int lrow = lane & 15, lk = (lane >> 4) * 8;
    f32x4 acc[2][8];
    #pragma unroll
    for (int a = 0; a < 2; ++a)
        #pragma unroll
        for (int b = 0; b < 8; ++b) acc[a][b] = (f32x4){0.f, 0.f, 0.f, 0.f};

    const int ktBeg = (wave == 3) ? 4 : 0;
    const int ktEnd = (wave == 2) ? 4 : 8;
    for (int kt = ktBeg; kt < ktEnd; ++kt) {
        bf16x8 ah[2], al[2];
        #pragma unroll
        for (int rt = 0; rt < 2; ++rt) {
            int row = rt * 16 + lrow;
            uint off = (uint)((row * 256 + kt * 32 + lk) * 2) ^ (uint)((row & 7) << 4);
            ah[rt] = *(const bf16x8*)(smem + off);
            al[rt] = *(const bf16x8*)(smem + 16384 + off);
        }
        const __bf16* bh_p = vfh + ((size_t)(kt * 32 + wave * 8) * 64 + lane) * 8;
        const __bf16* bl_p = vfl + ((size_t)(kt * 32 + wave * 8) * 64 + lane) * 8;
        #pragma unroll
        for (int ct = 0; ct < 8; ++ct) {
            bf16x8 bh = *(const bf16x8*)(bh_p + (size_t)ct * 512);
            bf16x8 bl = *(const bf16x8*)(bl_p + (size_t)ct * 512);
            #pragma unroll
            for (int rt = 0; rt < 2; ++rt) {
                acc[rt][ct] = mfma16(ah[rt], bh, acc[rt][ct]);
                acc[rt][ct] = mfma16(al[rt], bh, acc[rt][ct]);
                acc[rt][ct] = mfma16(ah[rt], bl, acc[rt][ct]);
            }
        }
    }
    __syncthreads();   // U dead; reuse LDS as gate-exchange buffer

    // ---- epilogue: 2 rounds of 64 cols ----
    #pragma unroll 1
    for (int rnd = 0; rnd < 2; ++rnd) {
        #pragma unroll
        for (int ct = rnd * 4; ct < rnd * 4 + 4; ++ct) {
            int cc = ct * 16 + lrow - rnd * 64;     // 0..63
            #pragma unroll
            for (int rt = 0; rt < 2; ++rt) {
                int n = rt * 16 + ((lane >> 4) << 2);
                #pragma unroll
                for (int reg = 0; reg < 4; ++reg)
                    ex[(n + reg) * 268 + cc * 4 + wave] = acc[rt][ct][reg];
            }
        }
        __syncthreads();
        {
            int c = rnd * 64 + lane;
            float4 b = *(const float4*)&bias4[c * 4];
            #pragma unroll 4
            for (int i = 0; i < 8; ++i) {
                int n = wave * 8 + i;
                int gr = brow + n;
                float4 g = *(const float4*)&ex[n * 268 + lane * 4];
                float rr = 1.f / (1.f + __expf(-(g.x + b.x)));
                float zz = 1.f / (1.f + __expf(-(g.y + b.y)));
                float nn = tanhf(g.z + b.z + rr * (g.w + b.w));
                if (gr < N) {
                    float h = xin[(size_t)gr * CDIM + c];
                    hout[(size_t)gr * CDIM + c] = (1.f - zz) * nn + zz * h;
                }
            }
        }
        __syncthreads();
    }
}

// ---------------------------------------------------------------------------
extern "C" void kernel_launch(void* const* d_in, const int* in_sizes, int n_in,
                              void* d_out, int out_size, void* d_ws, size_t ws_size,
                              hipStream_t stream) {
    const float* x      = (const float*)d_in[0];
    const int*   eidx   = (const int*)  d_in[1];
    const float* weight = (const float*)d_in[2];
    const float* w_ih   = (const float*)d_in[3];
    const float* w_hh   = (const float*)d_in[4];
    const float* b_ih   = (const float*)d_in[5];
    const float* b_hh   = (const float*)d_in[6];
    float* out = (float*)d_out;

    const int N = in_sizes[0] / CDIM;

    char* p = (char*)d_ws;
    float*  bufA  = (float*)p;  p += (size_t)N * CDIM * 4;
    float*  Wc    = (float*)p;  p += (size_t)NLAYER * CDIM * C3 * 4;
    float*  wT    = (float*)p;  p += (size_t)CDIM * C3 * 4;
    float*  bias4 = (float*)p;  p += 512 * 4;
    __bf16* vfh   = (__bf16*)p; p += (size_t)NLAYER * 131072 * 2;
    __bf16* vfl   = (__bf16*)p;

    prep_transpose<<<192, 256, 0, stream>>>(w_ih, wT);
    prep_wc<<<NLAYER * CDIM, 256, 0, stream>>>(weight, wT, Wc);
    prep_pack<<<192, 256, 0, stream>>>(Wc, w_hh, vfh, vfl);
    prep_bias<<<1, 128, 0, stream>>>(b_ih, b_hh, bias4);

    const int nb = (N + ROWS - 1) / ROWS;
    const size_t VSZ = 131072;   // per-layer fragment elements
    layer_kernel<<<nb, 256, 0, stream>>>(x,    eidx, vfh,           vfl,           bias4, out,  N);
    layer_kernel<<<nb, 256, 0, stream>>>(out,  eidx, vfh + VSZ,     vfl + VSZ,     bias4, bufA, N);
    layer_kernel<<<nb, 256, 0, stream>>>(bufA, eidx, vfh + 2 * VSZ, vfl + 2 * VSZ, bias4, out,  N);
}